// Round 5
// baseline (1606.525 us; speedup 1.0000x reference)
//
#include <hip/hip_runtime.h>
#include <math.h>

#define B_   4
#define M_   80
#define TMEL 63
#define R_   120
#define S_   240
#define Q_   256
#define NB_  16
#define L_   15872

typedef float  f32x4  __attribute__((ext_vector_type(4)));
typedef short  bf16x8 __attribute__((ext_vector_type(8)));
typedef short  short4_t __attribute__((ext_vector_type(4)));

// cheap bf16 round (half-up): 2 inst
__device__ __forceinline__ short f2bf(float x) {
  unsigned u = __builtin_bit_cast(unsigned, x) + 0x8000u;
  return (short)(u >> 16);
}
// pack two floats -> (lo | hi<<16) bf16 pair: 3 inst (add, add, v_perm)
__device__ __forceinline__ unsigned bfpack(float hi, float lo) {
  unsigned a = __builtin_bit_cast(unsigned, hi) + 0x8000u;
  unsigned b = __builtin_bit_cast(unsigned, lo) + 0x8000u;
  return __builtin_amdgcn_perm(a, b, 0x07060302u);
}
__device__ __forceinline__ float bf2f(unsigned short s) {
  unsigned u = ((unsigned)s) << 16;
  return __builtin_bit_cast(float, u);
}

// ---------------------------------------------------------------------------
// melT[b][i][m] bf16  <-  mel[b][m][i] f32
// ---------------------------------------------------------------------------
__global__ __launch_bounds__(256) void prep_melT_kernel(
    const float* __restrict__ mel, short* __restrict__ melT)
{
  const int idx = blockIdx.x * 256 + threadIdx.x;
  if (idx >= B_ * TMEL * M_) return;
  const int m = idx % M_;
  const int i = (idx / M_) % TMEL;
  const int b = idx / (M_ * TMEL);
  melT[idx] = f2bf(mel[b * (M_ * TMEL) + m * TMEL + i]);
}

// ---------------------------------------------------------------------------
// Wup[phi][c][j*80+m] bf16
// ---------------------------------------------------------------------------
__global__ __launch_bounds__(256) void prep_wup_kernel(
    const float* __restrict__ w_up, short* __restrict__ Wup)
{
  __shared__ float T[M_][65];
  const int c  = blockIdx.x >> 4;
  const int j  = (blockIdx.x >> 2) & 3;
  const int fb = blockIdx.x & 3;
  for (int idx = threadIdx.x; idx < M_ * 64; idx += 256) {
    const int pl = idx & 63, m = idx >> 6;
    const int phi = fb * 64 + pl;
    const int dmin = (phi < 112) ? -1 : -2;
    const int dmax = (phi < 144) ? 1 : 0;
    const int delta = dmin + j;
    float v = 0.0f;
    if (delta <= dmax)
      v = w_up[m * (M_ * 800) + c * 800 + (400 + phi + 256 * delta)];
    T[m][pl] = v;
  }
  __syncthreads();
  for (int idx = threadIdx.x; idx < 64 * M_; idx += 256) {
    const int m = idx % M_, pl = idx / M_;
    const int phi = fb * 64 + pl;
    Wup[((size_t)phi * M_ + c) * 320 + j * 80 + m] = f2bf(T[m][pl]);
  }
}

// ---------------------------------------------------------------------------
// Upsample as per-phase MFMA GEMM -> condb[b][t][80] bf16
// ---------------------------------------------------------------------------
#define KPU 328

__global__ __launch_bounds__(256, 2) void upsample_mfma_kernel(
    const short* __restrict__ melT, const short* __restrict__ Wup,
    const float* __restrict__ b_up, short* __restrict__ condb)
{
  __shared__ __align__(16) short Xu[64 * KPU];
  const int tid = threadIdx.x;
  const int phi = blockIdx.x;
  const int r0 = blockIdx.y * 64;
  const int dmin = (phi < 112) ? -1 : -2;

  for (int idx = tid; idx < 2560; idx += 256) {
    const int v = idx % 10;
    const int j = (idx / 10) & 3;
    const int rl = idx / 40;
    const int rho = r0 + rl;
    const int b = rho / 62;
    const int n = rho - b * 62;
    const int i = n - (dmin + j);
    int4 val = make_int4(0, 0, 0, 0);
    if (b < B_ && i >= 0 && i < TMEL)
      val = *(const int4*)&melT[((size_t)b * TMEL + i) * M_ + v * 8];
    *(int4*)&Xu[rl * KPU + j * 80 + v * 8] = val;
  }
  __syncthreads();

  const int lane = tid & 63;
  const int wv = tid >> 6;
  const int col = lane & 15;
  const int quad = lane >> 4;
  const int kq = quad * 8;

  f32x4 acc[5];
#pragma unroll
  for (int i = 0; i < 5; ++i) acc[i] = (f32x4)(0.f);
#pragma unroll
  for (int ks = 0; ks < 10; ++ks) {
    bf16x8 a = *(const bf16x8*)&Xu[(wv * 16 + col) * KPU + ks * 32 + kq];
#pragma unroll
    for (int ct = 0; ct < 5; ++ct) {
      bf16x8 b = *(const bf16x8*)(Wup + ((size_t)phi * M_ + ct * 16 + col) * 320 + ks * 32 + kq);
      acc[ct] = __builtin_amdgcn_mfma_f32_16x16x32_bf16(a, b, acc[ct], 0, 0, 0);
    }
  }
#pragma unroll
  for (int ct = 0; ct < 5; ++ct) {
    const int c = ct * 16 + col;
    const float bc = b_up[c];
#pragma unroll
    for (int reg = 0; reg < 4; ++reg) {
      const int rho = r0 + wv * 16 + quad * 4 + reg;
      if (rho < 248) {
        const int b = rho / 62;
        const int n = rho - b * 62;
        const int t = phi + (n << 8);
        condb[((size_t)b * L_ + t) * M_ + c] = f2bf(acc[ct][reg] + bc);
      }
    }
  }
}

// res0[b][t][128] fp32
__global__ __launch_bounds__(256) void in_conv_kernel(
    const float* __restrict__ wav, const float* __restrict__ w_in,
    const float* __restrict__ b_in, float* __restrict__ res)
{
  const int idx = blockIdx.x * 256 + threadIdx.x;
  const int r = idx & 127;
  const int rem = idx >> 7;
  const int t = rem % L_;
  const int b = rem / L_;
  res[idx] = (r < R_) ? (w_in[r] * wav[b * L_ + t] + b_in[r]) : 0.0f;
}

// ---------------------------------------------------------------------------
// Weight prepacks
// ---------------------------------------------------------------------------
__global__ __launch_bounds__(256) void prepack_w1_kernel(
    const float* __restrict__ wg, const float* __restrict__ wc,
    short* __restrict__ W1p)
{
  const int idx = blockIdx.x * 256 + threadIdx.x;   // 16*256*320
  const int k = idx % 320;
  const int cp = (idx / 320) % 256;
  const int i = idx / (320 * 256);
  float val = 0.0f;
  if (cp < 240) {
    const int r = cp >> 1;
    const int corig = (cp & 1) ? (120 + r) : r;
    if (k < 120)      val = wg[((size_t)(i * 240 + corig) * 120 + k) * 2 + 0];
    else if (k < 240) val = wg[((size_t)(i * 240 + corig) * 120 + (k - 120)) * 2 + 1];
    else              val = wc[(size_t)(i * 240 + corig) * 80 + (k - 240)];
  }
  W1p[idx] = f2bf(val);
}

__global__ __launch_bounds__(256) void prepack_w2_kernel(
    const float* __restrict__ wsk, const float* __restrict__ wr,
    short* __restrict__ W2p)
{
  const int idx = blockIdx.x * 256 + threadIdx.x;   // 16*384*128
  const int k = idx % 128;
  const int sp = (idx / 128) % 384;
  const int i = idx / (128 * 384);
  float val = 0.0f;
  if (k < 120) {
    if (sp < 240)      val = wsk[(size_t)(i * 240 + sp) * 120 + k];
    else if (sp < 360) val = wr[(size_t)(i * 120 + (sp - 240)) * 120 + k];
  }
  W2p[idx] = f2bf(val);
}

__global__ __launch_bounds__(256) void prepack_rest_kernel(
    const float* __restrict__ wh1, const float* __restrict__ wh2,
    const float* __restrict__ bg, const float* __restrict__ bc,
    const float* __restrict__ bs, const float* __restrict__ br,
    short* __restrict__ Wh1p, short* __restrict__ Wh2p,
    float* __restrict__ bias1p, float* __restrict__ bias2p)
{
  const int idx = blockIdx.x * 256 + threadIdx.x;   // 141056
  if (idx < 65536) {
    const int q = idx >> 8, k = idx & 255;
    Wh1p[idx] = f2bf(k < 240 ? wh1[q * 240 + k] : 0.0f);
  } else if (idx < 131072) {
    Wh2p[idx - 65536] = f2bf(wh2[idx - 65536]);
  } else if (idx < 134912) {
    const int j = idx - 131072;
    const int i = j / 240, cp = j % 240;
    const int r = cp >> 1;
    const int corig = (cp & 1) ? (120 + r) : r;
    bias1p[j] = bg[i * 240 + corig] + bc[i * 240 + corig];
  } else if (idx < 141056) {
    const int j = idx - 134912;
    const int i = j / 384, sp = j % 384;
    float v = 0.0f;
    if (sp < 240)      v = bs[i * 240 + sp];
    else if (sp < 360) v = br[i * 120 + (sp - 240)];
    bias2p[j] = v;
  }
}

// ---------------------------------------------------------------------------
// MFMA residual block. 512 thr / 8 waves; LDS = single 64x328 arena:
//   stage:  cols [0,120)=res[t-d], [120,240)=res[t], [240,320)=cond
//   B1 | GEMM1 | B2 | z -> overlay cols [184,312) (+pad zero [304,312))
//   B3 | GEMM2 | B4 | skip tiles -> overlay cols [0,240) ; res tiles -> global
//   B5 | cooperative int4 skips RMW
// 42 KB LDS -> 3 WG/CU (24 waves/CU). VGPR<=85 via __launch_bounds__(512,6).
// ---------------------------------------------------------------------------
#define KP1 328
#define ZOFF 184

__global__ __launch_bounds__(512, 6) void block_mfma_kernel(
    const float* __restrict__ res_in, float* __restrict__ res_out,
    unsigned short* __restrict__ skips, const short* __restrict__ condb,
    const short* __restrict__ W1, const short* __restrict__ W2,
    const float* __restrict__ bias1, const float* __restrict__ bias2,
    const int d, const int first)
{
  __shared__ __align__(16) short Xs[64 * KP1];

  const int tid = threadIdx.x;
  const int bb = blockIdx.y;
  const int t0 = blockIdx.x * 64;

  // ---- stage merged tap window + cond ----
  {
    const int dd = (d <= 64) ? d : 64;
    const int nr = 64 + dd;
    for (int idx = tid; idx < nr * 30; idx += 512) {
      const int rr = idx / 30, c4 = idx - rr * 30;
      int ts;
      if (d <= 64)      ts = t0 - d + rr;
      else              ts = (rr < 64) ? (t0 - 128 + rr) : (t0 + rr - 64);
      float4 v = make_float4(0.f, 0.f, 0.f, 0.f);
      if (ts >= 0)
        v = *(const float4*)(res_in + ((size_t)(bb * L_ + ts) * 128 + c4 * 4));
      uint2 p;
      p.x = bfpack(v.y, v.x);
      p.y = bfpack(v.w, v.z);
      if (rr < 64)
        *(uint2*)&Xs[rr * KP1 + c4 * 4] = p;                   // tap0
      const int r1 = rr - dd;
      if (r1 >= 0)
        *(uint2*)&Xs[r1 * KP1 + 120 + c4 * 4] = p;             // tap1
    }
  }
  for (int idx = tid; idx < 640; idx += 512) {
    const int c = idx % 10, trw = idx / 10;
    const int4 v = *(const int4*)(condb + ((size_t)(bb * L_ + t0 + trw) * M_ + c * 8));
    *(int4*)&Xs[trw * KP1 + 240 + c * 8] = v;
  }
  __syncthreads();                                             // B1

  const int lane = tid & 63;
  const int wv = tid >> 6;
  const int col = lane & 15;
  const int quad = lane >> 4;
  const int kq = quad * 8;

  // ---- GEMM1: wave wv -> c-tiles {2wv, 2wv+1}, t-tiles 0..3 ----
  f32x4 acc[4][2];
#pragma unroll
  for (int a = 0; a < 4; ++a)
#pragma unroll
    for (int b = 0; b < 2; ++b) acc[a][b] = (f32x4)(0.f);
#pragma unroll
  for (int ks = 0; ks < 10; ++ks) {
    bf16x8 av[4];
#pragma unroll
    for (int tf = 0; tf < 4; ++tf)
      av[tf] = *(const bf16x8*)&Xs[(tf * 16 + col) * KP1 + ks * 32 + kq];
#pragma unroll
    for (int ct = 0; ct < 2; ++ct) {
      bf16x8 b = *(const bf16x8*)(W1 + ((wv * 2 + ct) * 16 + col) * 320 + ks * 32 + kq);
#pragma unroll
      for (int tf = 0; tf < 4; ++tf)
        acc[tf][ct] = __builtin_amdgcn_mfma_f32_16x16x32_bf16(av[tf], b, acc[tf][ct], 0, 0, 0);
    }
  }

  // ---- gating into registers (even lanes hold z) ----
  float zv[2][4][4];
#pragma unroll
  for (int ct = 0; ct < 2; ++ct) {
    const int tile = wv * 2 + ct;
    if (tile < 15) {
      const float bias = bias1[tile * 16 + col];
#pragma unroll
      for (int tf = 0; tf < 4; ++tf) {
#pragma unroll
        for (int reg = 0; reg < 4; ++reg) {
          float v = acc[tf][ct][reg] + bias;
          v = fminf(fmaxf(v, -15.f), 15.f);
          const float e = __expf((lane & 1) ? -v : 2.0f * v);
          const float rc = __builtin_amdgcn_rcpf(e + 1.0f);
          const float u = (lane & 1) ? rc : (e - 1.0f) * rc;   // sig(g) | tanh(f)
          const float p = __shfl_xor(u, 1, 64);
          zv[ct][tf][reg] = u * p;
        }
      }
    }
  }
  __syncthreads();                                             // B2 (Xs reads done)

  // ---- write z into overlay Zs = Xs cols [ZOFF, ZOFF+128) ----
#pragma unroll
  for (int ct = 0; ct < 2; ++ct) {
    const int tile = wv * 2 + ct;
    if (tile < 15) {
#pragma unroll
      for (int tf = 0; tf < 4; ++tf)
#pragma unroll
        for (int reg = 0; reg < 4; ++reg)
          if (!(lane & 1)) {
            const int t = tf * 16 + quad * 4 + reg;
            Xs[t * KP1 + ZOFF + tile * 8 + (col >> 1)] = f2bf(zv[ct][tf][reg]);
          }
    }
  }
  if (tid < 64)   // zero k-pad cols [120,128) of Z
    *(int4*)&Xs[tid * KP1 + ZOFF + 120] = make_int4(0, 0, 0, 0);
  __syncthreads();                                             // B3

  // ---- GEMM2: wave wv -> s-tiles {3wv..3wv+2}, t-tiles 0..3 ----
  f32x4 acc2[4][3];
#pragma unroll
  for (int a = 0; a < 4; ++a)
#pragma unroll
    for (int b = 0; b < 3; ++b) acc2[a][b] = (f32x4)(0.f);
#pragma unroll
  for (int ks = 0; ks < 4; ++ks) {
    bf16x8 av[4];
#pragma unroll
    for (int tf = 0; tf < 4; ++tf)
      av[tf] = *(const bf16x8*)&Xs[(tf * 16 + col) * KP1 + ZOFF + ks * 32 + kq];
#pragma unroll
    for (int st = 0; st < 3; ++st) {
      bf16x8 b = *(const bf16x8*)(W2 + ((wv * 3 + st) * 16 + col) * 128 + ks * 32 + kq);
#pragma unroll
      for (int tf = 0; tf < 4; ++tf)
        acc2[tf][st] = __builtin_amdgcn_mfma_f32_16x16x32_bf16(av[tf], b, acc2[tf][st], 0, 0, 0);
    }
  }
  __syncthreads();                                             // B4 (Z reads done)

  // ---- skip tiles -> SG overlay (Xs cols [0,240)); res tiles -> global ----
#pragma unroll
  for (int st = 0; st < 3; ++st) {
    const int tile = wv * 3 + st;
    if (tile < 15) {
      const int s = tile * 16 + col;
      const float b2 = bias2[s];
#pragma unroll
      for (int tf = 0; tf < 4; ++tf)
#pragma unroll
        for (int reg = 0; reg < 4; ++reg)
          Xs[(tf * 16 + quad * 4 + reg) * KP1 + s] = f2bf(acc2[tf][st][reg] + b2);
    } else if (tile < 23) {
      const int s = tile * 16 + col;
      const int r = s - 240;
      if (r < 120) {
        const float b2 = bias2[s];
#pragma unroll
        for (int tf = 0; tf < 4; ++tf) {
#pragma unroll
          for (int reg = 0; reg < 4; ++reg) {
            const int t = tf * 16 + quad * 4 + reg;
            const size_t gi = ((size_t)(bb * L_ + t0 + t)) * 128 + r;
            res_out[gi] = res_in[gi] + acc2[tf][st][reg] + b2;
          }
        }
      }
    }
  }
  __syncthreads();                                             // B5

  // ---- cooperative vectorized skips RMW: 64 rows x 240 shorts ----
  {
    const size_t srow = ((size_t)bb * L_ + t0) * 240;
#pragma unroll
    for (int it = 0; it < 4; ++it) {
      const int idx = tid + it * 512;
      if (idx < 1920) {
        const int row = idx / 30;
        const int j = idx - row * 30;
        unsigned short* gp = skips + srow + row * 240 + j * 8;
        int4 sv = *(const int4*)&Xs[row * KP1 + j * 8];
        const unsigned short* svp = (const unsigned short*)&sv;
        float vals[8];
#pragma unroll
        for (int e = 0; e < 8; ++e) vals[e] = bf2f(svp[e]);
        if (!first) {
          int4 ov = *(const int4*)gp;
          const unsigned short* ovp = (const unsigned short*)&ov;
#pragma unroll
          for (int e = 0; e < 8; ++e) vals[e] += bf2f(ovp[e]);
        }
        int4 res;
        unsigned* rp = (unsigned*)&res;
#pragma unroll
        for (int e = 0; e < 4; ++e)
          rp[e] = bfpack(vals[2 * e + 1], vals[2 * e]);
        *(int4*)gp = res;
      }
    }
  }
}

// ---------------------------------------------------------------------------
// Head with 4-way q-split per wave.
// ---------------------------------------------------------------------------
#define KPH 264

__global__ __launch_bounds__(256, 2) void head_mfma_kernel(
    const unsigned short* __restrict__ skips,
    const short* __restrict__ Wh1, const short* __restrict__ Wh2,
    const float* __restrict__ bh1, const float* __restrict__ bh2,
    float* __restrict__ out)
{
  __shared__ __align__(16) short Ss[64 * KPH];
  __shared__ __align__(16) short Hs[64 * KPH];

  const int tid = threadIdx.x;
  const int bb = blockIdx.y;
  const int t0 = blockIdx.x * 64;

  for (int idx = tid; idx < 2048; idx += 256) {
    const int c = idx & 31, trw = idx >> 5;
    if (c < 30) {
      int4 v = *(const int4*)(skips + ((size_t)(bb * L_ + t0 + trw) * 240 + c * 8));
      int* vi = (int*)&v;
#pragma unroll
      for (int j = 0; j < 4; ++j) {
        unsigned x = (unsigned)vi[j];
        unsigned lo = x & 0xFFFFu; if (lo & 0x8000u) lo = 0;
        unsigned hi = x >> 16;     if (hi & 0x8000u) hi = 0;
        vi[j] = (int)(lo | (hi << 16));
      }
      *(int4*)&Ss[trw * KPH + c * 8] = v;
    } else {
      *(int4*)&Ss[trw * KPH + c * 8] = make_int4(0, 0, 0, 0);
    }
  }
  __syncthreads();

  const int lane = tid & 63;
  const int wv = tid >> 6;
  const int col = lane & 15;
  const int quad = lane >> 4;
  const int kq = quad * 8;

  f32x4 acc[4][4];
#pragma unroll
  for (int a = 0; a < 4; ++a)
#pragma unroll
    for (int b = 0; b < 4; ++b) acc[a][b] = (f32x4)(0.f);
#pragma unroll
  for (int ks = 0; ks < 8; ++ks) {
    bf16x8 av[4];
#pragma unroll
    for (int tf = 0; tf < 4; ++tf)
      av[tf] = *(const bf16x8*)&Ss[(tf * 16 + col) * KPH + ks * 32 + kq];
#pragma unroll
    for (int ct = 0; ct < 4; ++ct) {
      bf16x8 b = *(const bf16x8*)(Wh1 + ((wv * 4 + ct) * 16 + col) * 256 + ks * 32 + kq);
#pragma unroll
      for (int tf = 0; tf < 4; ++tf)
        acc[tf][ct] = __builtin_amdgcn_mfma_f32_16x16x32_bf16(av[tf], b, acc[tf][ct], 0, 0, 0);
    }
  }
#pragma unroll
  for (int ct = 0; ct < 4; ++ct) {
    const int q = (wv * 4 + ct) * 16 + col;
    const float b1 = bh1[q];
#pragma unroll
    for (int tf = 0; tf < 4; ++tf)
#pragma unroll
      for (int reg = 0; reg < 4; ++reg)
        Hs[(tf * 16 + quad * 4 + reg) * KPH + q] = f2bf(fmaxf(acc[tf][ct][reg] + b1, 0.0f));
  }
  __syncthreads();

  f32x4 acc2[4][4];
#pragma unroll
  for (int a = 0; a < 4; ++a)
#pragma unroll
    for (int b = 0; b < 4; ++b) acc2[a][b] = (f32x4)(0.f);
#pragma unroll
  for (int ks = 0; ks < 8; ++ks) {
    bf16x8 av[4];
#pragma unroll
    for (int tf = 0; tf < 4; ++tf)
      av[tf] = *(const bf16x8*)&Hs[(tf * 16 + col) * KPH + ks * 32 + kq];
#pragma unroll
    for (int ct = 0; ct < 4; ++ct) {
      bf16x8 b = *(const bf16x8*)(Wh2 + ((wv * 4 + ct) * 16 + col) * 256 + ks * 32 + kq);
#pragma unroll
      for (int tf = 0; tf < 4; ++tf)
        acc2[tf][ct] = __builtin_amdgcn_mfma_f32_16x16x32_bf16(av[tf], b, acc2[tf][ct], 0, 0, 0);
    }
  }
#pragma unroll
  for (int ct = 0; ct < 4; ++ct) {
    const int q = (wv * 4 + ct) * 16 + col;
    const float b2 = bh2[q];
#pragma unroll
    for (int tf = 0; tf < 4; ++tf) {
      const int tg0 = t0 + tf * 16 + quad * 4;
      float4 o = make_float4(acc2[tf][ct][0] + b2, acc2[tf][ct][1] + b2,
                             acc2[tf][ct][2] + b2, acc2[tf][ct][3] + b2);
      *(float4*)(out + ((size_t)(bb * Q_ + q)) * L_ + tg0) = o;
    }
  }
}

// ---------------------------------------------------------------------------
extern "C" void kernel_launch(void* const* d_in, const int* in_sizes, int n_in,
                              void* d_out, int out_size, void* d_ws, size_t ws_size,
                              hipStream_t stream) {
  const float* wav    = (const float*)d_in[0];
  const float* mel    = (const float*)d_in[1];
  const float* w_up   = (const float*)d_in[2];
  const float* b_up   = (const float*)d_in[3];
  const float* w_in   = (const float*)d_in[4];
  const float* b_in   = (const float*)d_in[5];
  const float* w_gate = (const float*)d_in[6];
  const float* b_gate = (const float*)d_in[7];
  const float* w_cond = (const float*)d_in[8];
  const float* b_cond = (const float*)d_in[9];
  const float* w_res  = (const float*)d_in[10];
  const float* b_res  = (const float*)d_in[11];
  const float* w_skip = (const float*)d_in[12];
  const float* b_skip = (const float*)d_in[13];
  const float* w_h1   = (const float*)d_in[14];
  const float* b_h1   = (const float*)d_in[15];
  const float* w_h2   = (const float*)d_in[16];
  const float* b_h2   = (const float*)d_in[17];
  float* out = (float*)d_out;

  char* w = (char*)d_ws;
  short* condb   = (short*)w;                 w += (size_t)B_ * L_ * M_ * 2;
  float* res0    = (float*)w;                 w += (size_t)B_ * L_ * 128 * 4;
  float* res1    = (float*)w;                 w += (size_t)B_ * L_ * 128 * 4;
  unsigned short* skips = (unsigned short*)w; w += (size_t)B_ * L_ * 240 * 2;
  short* W1p     = (short*)w;                 w += (size_t)16 * 256 * 320 * 2;
  short* W2p     = (short*)w;                 w += (size_t)16 * 384 * 128 * 2;
  short* Wh1p    = (short*)w;                 w += (size_t)256 * 256 * 2;
  short* Wh2p    = (short*)w;                 w += (size_t)256 * 256 * 2;
  float* bias1p  = (float*)w;                 w += (size_t)16 * 240 * 4;
  float* bias2p  = (float*)w;                 w += (size_t)16 * 384 * 4;
  short* melT    = (short*)w;                 w += (size_t)B_ * TMEL * M_ * 2;
  short* Wup = (short*)skips;   // overlay; consumed before first block kernel

  prepack_w1_kernel<<<(16 * 256 * 320) / 256, 256, 0, stream>>>(w_gate, w_cond, W1p);
  prepack_w2_kernel<<<(16 * 384 * 128) / 256, 256, 0, stream>>>(w_skip, w_res, W2p);
  prepack_rest_kernel<<<141056 / 256, 256, 0, stream>>>(
      w_h1, w_h2, b_gate, b_cond, b_skip, b_res, Wh1p, Wh2p, bias1p, bias2p);
  prep_melT_kernel<<<(B_ * TMEL * M_ + 255) / 256, 256, 0, stream>>>(mel, melT);
  prep_wup_kernel<<<80 * 4 * 4, 256, 0, stream>>>(w_up, Wup);

  dim3 ugrid(256, 4);
  upsample_mfma_kernel<<<ugrid, 256, 0, stream>>>(melT, Wup, b_up, condb);
  in_conv_kernel<<<((size_t)B_ * L_ * 128) / 256, 256, 0, stream>>>(wav, w_in, b_in, res0);

  dim3 bgrid(L_ / 64, B_);
  for (int i = 0; i < NB_; ++i) {
    const int d = 1 << (i & 7);
    const float* rin  = (i & 1) ? res1 : res0;
    float*       rout = (i & 1) ? res0 : res1;
    block_mfma_kernel<<<bgrid, 512, 0, stream>>>(
        rin, rout, skips, condb,
        W1p + (size_t)i * 256 * 320, W2p + (size_t)i * 384 * 128,
        bias1p + i * 240, bias2p + i * 384,
        d, (i == 0) ? 1 : 0);
  }

  head_mfma_kernel<<<bgrid, 256, 0, stream>>>(skips, Wh1p, Wh2p, b_h1, b_h2, out);
}